// Round 9
// baseline (189.966 us; speedup 1.0000x reference)
//
#include <hip/hip_runtime.h>

typedef unsigned short ushort_t;
typedef __attribute__((ext_vector_type(8))) __bf16 bf16x8;
typedef __attribute__((ext_vector_type(4))) float f32x4;
typedef __attribute__((ext_vector_type(16))) float f32x16;
typedef __attribute__((ext_vector_type(4))) float float4v;
typedef __attribute__((ext_vector_type(8))) unsigned short ushort8v;
typedef __attribute__((ext_vector_type(4))) unsigned short ushort4v;
typedef __attribute__((ext_vector_type(4))) unsigned uint4v;

#define T_LEN 2048
#define D_DIM 1024
#define NHEAD 16
#define HDIM 64
#define BH 64                    // B * H
#define MROWS 8192               // B * T
#define PERQKV ((size_t)BH * T_LEN * HDIM)   // 8388608 elems

__device__ __forceinline__ ushort_t f2bf(float f) {
  unsigned u = __builtin_bit_cast(unsigned, f);
  u = (u + 0x7FFFu + ((u >> 16) & 1u)) >> 16;
  return (ushort_t)u;
}

// raw v_exp_f32 (2^x): libm exp2f adds ~12 edge-case instrs per call (r7 lesson)
__device__ __forceinline__ float fast_exp2(float x) {
  float r; asm("v_exp_f32 %0, %1" : "=v"(r) : "v"(x)); return r;
}

__device__ __forceinline__ void load_lds16(const ushort_t* g, ushort_t* l) {
  __builtin_amdgcn_global_load_lds((const __attribute__((address_space(1))) void*)g,
                                   (__attribute__((address_space(3))) void*)l, 16, 0, 0);
}

// ---------------- convert x (f32 -> bf16), 4 elems/thread ----------------
__global__ __launch_bounds__(256) void k_cvt_x(const float* __restrict__ x,
                                               ushort_t* __restrict__ xb) {
  int i = blockIdx.x * 256 + threadIdx.x;
  float4v v = ((const float4v*)x)[i];
  ushort4v o;
  o[0] = f2bf(v[0]); o[1] = f2bf(v[1]); o[2] = f2bf(v[2]); o[3] = f2bf(v[3]);
  ((ushort4v*)xb)[i] = o;
}

// ------------- transpose + convert: W[R][C] f32 -> Wt[C][R] bf16 -------------
__global__ __launch_bounds__(256) void k_transpose(const float* __restrict__ W,
                                                   ushort_t* __restrict__ Wt,
                                                   int R, int C) {
  __shared__ ushort_t tile[32][33];
  int tx = threadIdx.x & 31, ty = threadIdx.x >> 5;
  int r0 = blockIdx.y << 5, c0 = blockIdx.x << 5;
#pragma unroll
  for (int i = 0; i < 4; ++i) {
    int r = ty + i * 8;
    tile[r][tx] = f2bf(W[(size_t)(r0 + r) * C + c0 + tx]);
  }
  __syncthreads();
#pragma unroll
  for (int i = 0; i < 4; ++i) {
    int r = ty + i * 8;
    Wt[(size_t)(c0 + r) * R + r0 + tx] = tile[tx][r];
  }
}

// ---------------- GEMM: C[M][N] = A[M][K] * Bt[N][K]^T, bf16 MFMA ----------------
template <int N, int K, int EPI>
__global__ __launch_bounds__(256) void k_gemm(const ushort_t* __restrict__ A,
                                              const ushort_t* __restrict__ Bt,
                                              ushort_t* __restrict__ O16,
                                              float* __restrict__ O32) {
  __shared__ __align__(16) ushort_t Atile[128 * 32];
  __shared__ __align__(16) ushort_t Btile[128 * 32];
  const int tid = threadIdx.x;
  const int lane = tid & 63, w = tid >> 6;
  const int g = lane >> 4, c = lane & 15;
  const int wm = w >> 1, wn = w & 1;
  const int m0 = blockIdx.y * 128, n0 = blockIdx.x * 128;

  f32x4 acc[4][4];
#pragma unroll
  for (int i = 0; i < 4; ++i)
#pragma unroll
    for (int j = 0; j < 4; ++j) acc[i][j] = (f32x4){0.f, 0.f, 0.f, 0.f};

  for (int k0 = 0; k0 < K; k0 += 32) {
    __syncthreads();
#pragma unroll
    for (int r = 0; r < 2; ++r) {
      int flat = r * 256 + tid;
      int row = flat >> 2, slot = flat & 3;
      int gsl = slot ^ (row & 3);                 // source-swizzle (rule #21)
      load_lds16(A + (size_t)(m0 + row) * K + k0 + gsl * 8,
                 &Atile[(r * 256 + w * 64) * 8]);
      load_lds16(Bt + (size_t)(n0 + row) * K + k0 + gsl * 8,
                 &Btile[(r * 256 + w * 64) * 8]);
    }
    __syncthreads();

    bf16x8 af[4], bfr[4];
#pragma unroll
    for (int mi = 0; mi < 4; ++mi) {
      int row = wm * 64 + mi * 16 + c;
      int sl = g ^ (row & 3);
      af[mi] = *(const bf16x8*)&Atile[row * 32 + sl * 8];
    }
#pragma unroll
    for (int ni = 0; ni < 4; ++ni) {
      int row = wn * 64 + ni * 16 + c;
      int sl = g ^ (row & 3);
      bfr[ni] = *(const bf16x8*)&Btile[row * 32 + sl * 8];
    }
#pragma unroll
    for (int mi = 0; mi < 4; ++mi)
#pragma unroll
      for (int ni = 0; ni < 4; ++ni)
        acc[mi][ni] = __builtin_amdgcn_mfma_f32_16x16x32_bf16(af[mi], bfr[ni],
                                                              acc[mi][ni], 0, 0, 0);
  }

#pragma unroll
  for (int mi = 0; mi < 4; ++mi)
#pragma unroll
    for (int ni = 0; ni < 4; ++ni) {
      int n = n0 + wn * 64 + ni * 16 + c;
#pragma unroll
      for (int j = 0; j < 4; ++j) {
        int m = m0 + wm * 64 + mi * 16 + g * 4 + j;
        float v = acc[mi][ni][j];
        if constexpr (EPI == 0) {
          int which = n >> 10, hn = n & 1023;
          int h = hn >> 6, d = hn & 63;
          int b = m >> 11, t = m & 2047;
          if (which == 0) v *= 0.18033688f;   // 1/sqrt(64) * log2(e) folded into Q
          O16[(size_t)which * PERQKV +
              (((size_t)(b * NHEAD + h) * T_LEN + t) * HDIM + d)] = f2bf(v);
        } else {
          O32[(size_t)m * N + n] = v;
        }
      }
    }
}

// ---------------- flash attention v8: single-buffer 16KB, fully-resident grid ----
// QBLK=64 (2 waves x 32 q-rows), KVBLK=64, grid 2048 big-p-first.
// LDS 16KB (K 8KB + V 8KB, single-buffered) -> 8 blocks/CU resident
// (VGPR-capped 4 waves/SIMD; LDS would allow 10) -> ALL blocks resident.
// K staged via global_load_lds (pre-swizzled source, zero VGPR); V reg-staged
// with issue-early/write-late (T14). 2 barriers/iter; TLP (16 waves/CU) hides
// the staging drains. T5 setprio around MFMA clusters.
__global__ __launch_bounds__(128) void k_attn(const ushort_t* __restrict__ Q,
                                              const ushort_t* __restrict__ Kv,
                                              const ushort_t* __restrict__ Vv,
                                              ushort_t* __restrict__ Y) {
  __shared__ __align__(16) ushort_t Kt[64 * 64];   // [k][d], granule swz ^(k&7)
  __shared__ __align__(16) ushort_t Vt[64 * 64];   // [d][k], granule swz ^(d&7)

  const int bid = blockIdx.x;                          // 0..2047
  const int bh = (bid & 7) * 8 + ((bid >> 3) & 7);     // 8 bh per XCD (L2-fit)
  const int p = 31 - (bid >> 6);                       // q-tile (64 rows), big-first
  const int nkt = p + 1;

  const int tid = threadIdx.x, lane = tid & 63, w = tid >> 6;  // w in {0,1}
  const int hi = lane >> 5, lc = lane & 31;
  const int q32 = p * 64 + w * 32;
  const size_t base = (size_t)bh * (T_LEN * HDIM);

  // Q^T B-fragments (Q pre-scaled by 0.125*log2e): q-row = lc, hd = st*16+hi*8+e
  bf16x8 qf[4];
#pragma unroll
  for (int st = 0; st < 4; ++st)
    qf[st] = *(const bf16x8*)(Q + base + (size_t)(q32 + lc) * HDIM + st * 16 + hi * 8);

  f32x16 o0, o1;
#pragma unroll
  for (int i = 0; i < 16; ++i) { o0[i] = 0.f; o1[i] = 0.f; }
  float mrun = 0.f, lrun = 0.f;   // scores bounded ~7 << THR=11

  // ---- K staging via global_load_lds: wave-uniform dest base + lane*16B ----
  // dest granule = m*128 + w*64 + lane -> row = m*16 + w*8 + (lane>>3), slot = lane&7
  // source slot = (lane&7) ^ (row&7)  (rule #21: inverse-swizzled source)
  const int krow_g = w * 8 + (lane >> 3);
  const int ksrc_off = (((lane & 7) ^ (krow_g & 7)) << 3);
  auto stage_K = [&](int kt) {
    const ushort_t* kb = Kv + base + (size_t)kt * 64 * HDIM;
#pragma unroll
    for (int m = 0; m < 4; ++m)
      load_lds16(kb + (size_t)(m * 16 + krow_g) * HDIM + ksrc_off,
                 &Kt[(m * 128 + w * 64) * 8]);
  };

  // ---- V reg-staging (transpose in regs; 16 u32 ds_writes) ----
  const int kpair = tid & 31, vk0 = 2 * kpair, vd0 = (tid >> 5) * 8;  // V: d0, d0+32
  ushort8v vreg[4];
  auto issue_V = [&](int kt) {
    const ushort_t* vb = Vv + base + (size_t)kt * 64 * HDIM;
    vreg[0] = *(const ushort8v*)(vb + (size_t)vk0 * HDIM + vd0);
    vreg[1] = *(const ushort8v*)(vb + (size_t)(vk0 + 1) * HDIM + vd0);
    vreg[2] = *(const ushort8v*)(vb + (size_t)vk0 * HDIM + vd0 + 32);
    vreg[3] = *(const ushort8v*)(vb + (size_t)(vk0 + 1) * HDIM + vd0 + 32);
  };
  auto write_V = [&]() {
#pragma unroll
    for (int e = 0; e < 8; ++e) {
      int rd = vd0 + e;
      unsigned pv = (unsigned)vreg[0][e] | ((unsigned)vreg[1][e] << 16);
      *(unsigned*)&Vt[rd * 64 + (((kpair >> 2) ^ (rd & 7)) << 3) + 2 * (kpair & 3)] = pv;
      int rd2 = rd + 32;
      unsigned pv2 = (unsigned)vreg[2][e] | ((unsigned)vreg[3][e] << 16);
      *(unsigned*)&Vt[rd2 * 64 + (((kpair >> 2) ^ (rd2 & 7)) << 3) + 2 * (kpair & 3)] = pv2;
    }
  };

  // prologue: tile 0 into LDS
  stage_K(0);
  issue_V(0);
  write_V();
  __syncthreads();   // drains K DMA (vmcnt) + V ds_writes (lgkm)

  for (int kt = 0; kt < nkt; ++kt) {
    if (kt + 1 < nkt) issue_V(kt + 1);   // T14: issue early, hidden by compute

    // ---- S^T[k][q]: A = K-frag (row k=lc, c=hd), B = Q^T-frag ----
    f32x16 s0, s1;
#pragma unroll
    for (int i = 0; i < 16; ++i) { s0[i] = 0.f; s1[i] = 0.f; }
    __builtin_amdgcn_s_setprio(1);
#pragma unroll
    for (int st = 0; st < 4; ++st) {
      bf16x8 kf0 = *(const bf16x8*)&Kt[lc * 64 + (((2 * st + hi) ^ (lc & 7)) << 3)];
      s0 = __builtin_amdgcn_mfma_f32_32x32x16_bf16(kf0, qf[st], s0, 0, 0, 0);
    }
#pragma unroll
    for (int st = 0; st < 4; ++st) {
      bf16x8 kf1 = *(const bf16x8*)&Kt[(32 + lc) * 64 + (((2 * st + hi) ^ (lc & 7)) << 3)];
      s1 = __builtin_amdgcn_mfma_f32_32x32x16_bf16(kf1, qf[st], s1, 0, 0, 0);
    }
    __builtin_amdgcn_s_setprio(0);

    // ---- causal mask: only the diagonal tile crosses ----
    if (kt * 64 + 63 > q32) {
      const int q = q32 + lc;
#pragma unroll
      for (int r = 0; r < 16; ++r) {
        int cr = (r & 3) + 8 * (r >> 2) + 4 * hi;
        if (kt * 64 + cr > q)      s0[r] = -3.0e38f;
        if (kt * 64 + 32 + cr > q) s1[r] = -3.0e38f;
      }
    }

    // ---- tile max (in-lane tree + cross-half) ----
    float tm[8];
#pragma unroll
    for (int i = 0; i < 8; ++i) tm[i] = fmaxf(fmaxf(s0[i], s0[i + 8]), fmaxf(s1[i], s1[i + 8]));
#pragma unroll
    for (int i = 0; i < 4; ++i) tm[i] = fmaxf(tm[i], tm[i + 4]);
    float tmax = fmaxf(fmaxf(tm[0], tm[1]), fmaxf(tm[2], tm[3]));
    tmax = fmaxf(tmax, __shfl_xor(tmax, 32));

    // ---- T13 defer-max rescale (log2 domain, THR=11; rare with mrun=0) ----
    if (!__all(tmax <= mrun + 11.0f)) {
      float mnew = fmaxf(mrun, tmax);
      float sc = fast_exp2(mrun - mnew);
      lrun *= sc; mrun = mnew;
#pragma unroll
      for (int r = 0; r < 16; ++r) {
        int cr = (r & 3) + 8 * (r >> 2) + 4 * hi;
        float scr = __shfl(sc, cr);
        o0[r] *= scr; o1[r] *= scr;
      }
    }

    // ---- P = exp2(S - m), partial row-sums (deferred cross-half) ----
#pragma unroll
    for (int r = 0; r < 16; ++r) s0[r] = fast_exp2(s0[r] - mrun);
#pragma unroll
    for (int r = 0; r < 16; ++r) s1[r] = fast_exp2(s1[r] - mrun);
    {
      float u0 = 0.f, u1 = 0.f, u2 = 0.f, u3 = 0.f;
#pragma unroll
      for (int i = 0; i < 4; ++i) {
        u0 += s0[i];     u1 += s0[i + 4];  u2 += s0[i + 8];  u3 += s0[i + 12];
        u0 += s1[i];     u1 += s1[i + 4];  u2 += s1[i + 8];  u3 += s1[i + 12];
      }
      lrun += (u0 + u1) + (u2 + u3);
    }

    // ---- pack P to bf16 pairs; permlane32_swap redistributes to A-frags ----
    unsigned wv[16];
#pragma unroll
    for (int i = 0; i < 8; ++i) {
      asm("v_cvt_pk_bf16_f32 %0, %1, %2" : "=v"(wv[i])     : "v"(s0[2 * i]), "v"(s0[2 * i + 1]));
      asm("v_cvt_pk_bf16_f32 %0, %1, %2" : "=v"(wv[8 + i]) : "v"(s1[2 * i]), "v"(s1[2 * i + 1]));
    }
    bf16x8 pf[4];
#pragma unroll
    for (int g4 = 0; g4 < 4; ++g4) {
      unsigned a0 = wv[4 * g4], a1 = wv[4 * g4 + 1];
      unsigned a2 = wv[4 * g4 + 2], a3 = wv[4 * g4 + 3];
      asm("v_permlane32_swap_b32 %0, %1" : "+v"(a0), "+v"(a2));
      asm("v_permlane32_swap_b32 %0, %1" : "+v"(a1), "+v"(a3));
      uint4v fw; fw[0] = a0; fw[1] = a1; fw[2] = a2; fw[3] = a3;
      pf[g4] = __builtin_bit_cast(bf16x8, fw);
    }

    // ---- O += P V (V from [d][k] granule-swizzled LDS, b128 reads) ----
    __builtin_amdgcn_s_setprio(1);
#pragma unroll
    for (int km = 0; km < 4; ++km) {
      int gsl = ((2 * km + hi) ^ (lc & 7)) << 3;
      bf16x8 vb0 = *(const bf16x8*)&Vt[lc * 64 + gsl];
      bf16x8 vb1 = *(const bf16x8*)&Vt[(32 + lc) * 64 + gsl];
      o0 = __builtin_amdgcn_mfma_f32_32x32x16_bf16(pf[km], vb0, o0, 0, 0, 0);
      o1 = __builtin_amdgcn_mfma_f32_32x32x16_bf16(pf[km], vb1, o1, 0, 0, 0);
    }
    __builtin_amdgcn_s_setprio(0);

    // ---- overwrite single buffers with tile kt+1 ----
    __syncthreads();                       // all waves done reading Kt/Vt
    if (kt + 1 < nkt) { stage_K(kt + 1); write_V(); }
    __syncthreads();                       // K DMA + V writes visible
  }

  // ---- epilogue: combine halves of l, scale, store ----
  float lt = lrun + __shfl_xor(lrun, 32);
  float invl = 1.f / lt;
  const int b_ = bh >> 4, h_ = bh & 15;
#pragma unroll
  for (int r = 0; r < 16; ++r) {
    int cr = (r & 3) + 8 * (r >> 2) + 4 * hi;
    float iv = __shfl(invl, cr);
    size_t m = (size_t)b_ * T_LEN + q32 + cr;
    Y[m * D_DIM + h_ * HDIM + lc]      = f2bf(o0[r] * iv);
    Y[m * D_DIM + h_ * HDIM + 32 + lc] = f2bf(o1[r] * iv);
  }
}

extern "C" void kernel_launch(void* const* d_in, const int* in_sizes, int n_in,
                              void* d_out, int out_size, void* d_ws, size_t ws_size,
                              hipStream_t stream) {
  const float* x     = (const float*)d_in[0];
  const float* Wqkv  = (const float*)d_in[1];
  const float* Wproj = (const float*)d_in[2];
  float* out = (float*)d_out;
  ushort_t* ws = (ushort_t*)d_ws;

  ushort_t* Xb  = ws;
  ushort_t* WqT = Xb  + (size_t)MROWS * D_DIM;        // 8192*1024
  ushort_t* WpT = WqT + (size_t)3 * D_DIM * D_DIM;    // 3072*1024
  ushort_t* Qb  = WpT + (size_t)D_DIM * D_DIM;        // 1024*1024
  ushort_t* Kb  = Qb + PERQKV;
  ushort_t* Vb  = Kb + PERQKV;
  ushort_t* Yb  = Vb + PERQKV;

  k_cvt_x<<<(MROWS * D_DIM / 4) / 256, 256, 0, stream>>>(x, Xb);
  k_transpose<<<dim3(3 * D_DIM / 32, D_DIM / 32), 256, 0, stream>>>(Wqkv, WqT, D_DIM, 3 * D_DIM);
  k_transpose<<<dim3(D_DIM / 32, D_DIM / 32), 256, 0, stream>>>(Wproj, WpT, D_DIM, D_DIM);
  k_gemm<3 * D_DIM, D_DIM, 0><<<dim3(3 * D_DIM / 128, MROWS / 128), 256, 0, stream>>>(Xb, WqT, Qb, nullptr);
  k_attn<<<2048, 128, 0, stream>>>(Qb, Kb, Vb, Yb);
  k_gemm<D_DIM, D_DIM, 1><<<dim3(D_DIM / 128, MROWS / 128), 256, 0, stream>>>(Yb, WpT, nullptr, out);
}

// Round 10
// 189.116 us; speedup vs baseline: 1.0045x; 1.0045x over previous
//
#include <hip/hip_runtime.h>

typedef unsigned short ushort_t;
typedef __attribute__((ext_vector_type(8))) __bf16 bf16x8;
typedef __attribute__((ext_vector_type(4))) float f32x4;
typedef __attribute__((ext_vector_type(16))) float f32x16;
typedef __attribute__((ext_vector_type(4))) float float4v;
typedef __attribute__((ext_vector_type(8))) unsigned short ushort8v;
typedef __attribute__((ext_vector_type(4))) unsigned short ushort4v;
typedef __attribute__((ext_vector_type(4))) unsigned uint4v;

#define T_LEN 2048
#define D_DIM 1024
#define NHEAD 16
#define HDIM 64
#define BH 64                    // B * H
#define MROWS 8192               // B * T
#define PERQKV ((size_t)BH * T_LEN * HDIM)   // 8388608 elems

__device__ __forceinline__ ushort_t f2bf(float f) {
  unsigned u = __builtin_bit_cast(unsigned, f);
  u = (u + 0x7FFFu + ((u >> 16) & 1u)) >> 16;
  return (ushort_t)u;
}

// raw v_exp_f32 (2^x): libm exp2f adds ~12 edge-case instrs per call (r7 lesson)
__device__ __forceinline__ float fast_exp2(float x) {
  float r; asm("v_exp_f32 %0, %1" : "=v"(r) : "v"(x)); return r;
}

__device__ __forceinline__ void load_lds16(const ushort_t* g, ushort_t* l) {
  __builtin_amdgcn_global_load_lds((const __attribute__((address_space(1))) void*)g,
                                   (__attribute__((address_space(3))) void*)l, 16, 0, 0);
}

// ---------------- convert x (f32 -> bf16), 4 elems/thread ----------------
__global__ __launch_bounds__(256) void k_cvt_x(const float* __restrict__ x,
                                               ushort_t* __restrict__ xb) {
  int i = blockIdx.x * 256 + threadIdx.x;
  float4v v = ((const float4v*)x)[i];
  ushort4v o;
  o[0] = f2bf(v[0]); o[1] = f2bf(v[1]); o[2] = f2bf(v[2]); o[3] = f2bf(v[3]);
  ((ushort4v*)xb)[i] = o;
}

// ------------- transpose + convert: W[R][C] f32 -> Wt[C][R] bf16 -------------
__global__ __launch_bounds__(256) void k_transpose(const float* __restrict__ W,
                                                   ushort_t* __restrict__ Wt,
                                                   int R, int C) {
  __shared__ ushort_t tile[32][33];
  int tx = threadIdx.x & 31, ty = threadIdx.x >> 5;
  int r0 = blockIdx.y << 5, c0 = blockIdx.x << 5;
#pragma unroll
  for (int i = 0; i < 4; ++i) {
    int r = ty + i * 8;
    tile[r][tx] = f2bf(W[(size_t)(r0 + r) * C + c0 + tx]);
  }
  __syncthreads();
#pragma unroll
  for (int i = 0; i < 4; ++i) {
    int r = ty + i * 8;
    Wt[(size_t)(c0 + r) * R + r0 + tx] = tile[tx][r];
  }
}

// ---------------- GEMM: C[M][N] = A[M][K] * Bt[N][K]^T, bf16 MFMA ----------------
template <int N, int K, int EPI>
__global__ __launch_bounds__(256) void k_gemm(const ushort_t* __restrict__ A,
                                              const ushort_t* __restrict__ Bt,
                                              ushort_t* __restrict__ O16,
                                              float* __restrict__ O32) {
  __shared__ __align__(16) ushort_t Atile[128 * 32];
  __shared__ __align__(16) ushort_t Btile[128 * 32];
  const int tid = threadIdx.x;
  const int lane = tid & 63, w = tid >> 6;
  const int g = lane >> 4, c = lane & 15;
  const int wm = w >> 1, wn = w & 1;
  const int m0 = blockIdx.y * 128, n0 = blockIdx.x * 128;

  f32x4 acc[4][4];
#pragma unroll
  for (int i = 0; i < 4; ++i)
#pragma unroll
    for (int j = 0; j < 4; ++j) acc[i][j] = (f32x4){0.f, 0.f, 0.f, 0.f};

  for (int k0 = 0; k0 < K; k0 += 32) {
    __syncthreads();
#pragma unroll
    for (int r = 0; r < 2; ++r) {
      int flat = r * 256 + tid;
      int row = flat >> 2, slot = flat & 3;
      int gsl = slot ^ (row & 3);                 // source-swizzle (rule #21)
      load_lds16(A + (size_t)(m0 + row) * K + k0 + gsl * 8,
                 &Atile[(r * 256 + w * 64) * 8]);
      load_lds16(Bt + (size_t)(n0 + row) * K + k0 + gsl * 8,
                 &Btile[(r * 256 + w * 64) * 8]);
    }
    __syncthreads();

    bf16x8 af[4], bfr[4];
#pragma unroll
    for (int mi = 0; mi < 4; ++mi) {
      int row = wm * 64 + mi * 16 + c;
      int sl = g ^ (row & 3);
      af[mi] = *(const bf16x8*)&Atile[row * 32 + sl * 8];
    }
#pragma unroll
    for (int ni = 0; ni < 4; ++ni) {
      int row = wn * 64 + ni * 16 + c;
      int sl = g ^ (row & 3);
      bfr[ni] = *(const bf16x8*)&Btile[row * 32 + sl * 8];
    }
#pragma unroll
    for (int mi = 0; mi < 4; ++mi)
#pragma unroll
      for (int ni = 0; ni < 4; ++ni)
        acc[mi][ni] = __builtin_amdgcn_mfma_f32_16x16x32_bf16(af[mi], bfr[ni],
                                                              acc[mi][ni], 0, 0, 0);
  }

#pragma unroll
  for (int mi = 0; mi < 4; ++mi)
#pragma unroll
    for (int ni = 0; ni < 4; ++ni) {
      int n = n0 + wn * 64 + ni * 16 + c;
#pragma unroll
      for (int j = 0; j < 4; ++j) {
        int m = m0 + wm * 64 + mi * 16 + g * 4 + j;
        float v = acc[mi][ni][j];
        if constexpr (EPI == 0) {
          int which = n >> 10, hn = n & 1023;
          int h = hn >> 6, d = hn & 63;
          int b = m >> 11, t = m & 2047;
          if (which == 0) v *= 0.18033688f;   // 1/sqrt(64) * log2(e) folded into Q
          O16[(size_t)which * PERQKV +
              (((size_t)(b * NHEAD + h) * T_LEN + t) * HDIM + d)] = f2bf(v);
        } else {
          O32[(size_t)m * N + n] = v;
        }
      }
    }
}

// ---------------- flash attention v9: paired q-tiles, 4 uniform blocks/CU ----------------
// QBLK=64 (2 waves x 32 q-rows), KVBLK=64, double-buffered reg-staging, ONE
// barrier/iter. Block handles q-tile pA=31-i then pB=i: exactly 34 tile-iters.
// Grid 1024 = 4 blocks/CU resident for the WHOLE kernel (8 waves/CU constant):
// fixes r8/r9's triangular drain (avg 3 blocks/CU) and r7's starvation (2/CU).
// LDS 32KB x 4 = 128KB <= 160KB; __launch_bounds__(128,4) pins VGPR <= 128.
__global__ __launch_bounds__(128, 4) void k_attn(const ushort_t* __restrict__ Q,
                                                 const ushort_t* __restrict__ Kv,
                                                 const ushort_t* __restrict__ Vv,
                                                 ushort_t* __restrict__ Y) {
  __shared__ __align__(16) ushort_t Kt[2][64 * 64];   // [k][d], granule swz ^(k&7)
  __shared__ __align__(16) ushort_t Vt[2][64 * 64];   // [d][k], granule swz ^(d&7)

  const int bid = blockIdx.x;                          // 0..1023
  const int bh = (bid & 7) * 8 + ((bid >> 3) & 7);     // 8 bh per XCD (L2-fit)
  const int pairidx = bid >> 6;                        // 0..15
  const int pA = 31 - pairidx, pB = pairidx;
  const int nktA = pA + 1;
  const int total = nktA + pB + 1;                     // 34 for every block

  const int tid = threadIdx.x, lane = tid & 63, w = tid >> 6;  // w in {0,1}
  const int hi = lane >> 5, lc = lane & 31;
  const size_t base = (size_t)bh * (T_LEN * HDIM);

  int q32 = pA * 64 + w * 32;
  // Q^T B-fragments (Q pre-scaled by 0.125*log2e): q-row = lc, hd = st*16+hi*8+e
  bf16x8 qf[4];
#pragma unroll
  for (int st = 0; st < 4; ++st)
    qf[st] = *(const bf16x8*)(Q + base + (size_t)(q32 + lc) * HDIM + st * 16 + hi * 8);

  f32x16 o0, o1;
#pragma unroll
  for (int i = 0; i < 16; ++i) { o0[i] = 0.f; o1[i] = 0.f; }
  float mrun = 0.f, lrun = 0.f;   // scores bounded ~7 << THR=11

  // staging decomposition (128 threads)
  const int ksl = tid & 7, krow0 = tid >> 3;           // K: rows krow0+16m
  const int kpair = tid & 31, vk0 = 2 * kpair, vd0 = (tid >> 5) * 8;  // V: d0, d0+32

  bf16x8 kreg[4];
  ushort8v vreg[4];
  auto stage_issue = [&](int kt) {
    const ushort_t* kb = Kv + base + (size_t)kt * 64 * HDIM;
    const ushort_t* vb = Vv + base + (size_t)kt * 64 * HDIM;
    vreg[0] = *(const ushort8v*)(vb + (size_t)vk0 * HDIM + vd0);
    vreg[1] = *(const ushort8v*)(vb + (size_t)(vk0 + 1) * HDIM + vd0);
    vreg[2] = *(const ushort8v*)(vb + (size_t)vk0 * HDIM + vd0 + 32);
    vreg[3] = *(const ushort8v*)(vb + (size_t)(vk0 + 1) * HDIM + vd0 + 32);
#pragma unroll
    for (int m = 0; m < 4; ++m)
      kreg[m] = *(const bf16x8*)(kb + (size_t)(krow0 + 16 * m) * HDIM + ksl * 8);
  };
  auto stage_write = [&](int buf) {
#pragma unroll
    for (int m = 0; m < 4; ++m) {
      int r = krow0 + 16 * m;
      *(bf16x8*)&Kt[buf][r * 64 + ((ksl ^ (r & 7)) << 3)] = kreg[m];
    }
#pragma unroll
    for (int e = 0; e < 8; ++e) {
      int rd = vd0 + e;
      unsigned pv = (unsigned)vreg[0][e] | ((unsigned)vreg[1][e] << 16);
      *(unsigned*)&Vt[buf][rd * 64 + (((kpair >> 2) ^ (rd & 7)) << 3) + 2 * (kpair & 3)] = pv;
      int rd2 = rd + 32;
      unsigned pv2 = (unsigned)vreg[2][e] | ((unsigned)vreg[3][e] << 16);
      *(unsigned*)&Vt[buf][rd2 * 64 + (((kpair >> 2) ^ (rd2 & 7)) << 3) + 2 * (kpair & 3)] = pv2;
    }
  };

  const int b_ = bh >> 4, h_ = bh & 15;
  auto epilogue = [&]() {
    float lt = lrun + __shfl_xor(lrun, 32);
    float invl = 1.f / lt;
#pragma unroll
    for (int r = 0; r < 16; ++r) {
      int cr = (r & 3) + 8 * (r >> 2) + 4 * hi;
      float iv = __shfl(invl, cr);
      size_t m = (size_t)b_ * T_LEN + q32 + cr;
      Y[m * D_DIM + h_ * HDIM + lc]      = f2bf(o0[r] * iv);
      Y[m * D_DIM + h_ * HDIM + 32 + lc] = f2bf(o1[r] * iv);
    }
  };

  stage_issue(0); stage_write(0);
  stage_issue(1);                        // nktA >= 17, always valid
  __syncthreads();

  for (int it = 0; it < total; ++it) {
    // phase switch: finish pA, start pB
    if (it == nktA) {
      epilogue();
      q32 = pB * 64 + w * 32;
#pragma unroll
      for (int st = 0; st < 4; ++st)
        qf[st] = *(const bf16x8*)(Q + base + (size_t)(q32 + lc) * HDIM + st * 16 + hi * 8);
#pragma unroll
      for (int i = 0; i < 16; ++i) { o0[i] = 0.f; o1[i] = 0.f; }
      mrun = 0.f; lrun = 0.f;
    }
    const int kt = (it < nktA) ? it : it - nktA;
    const int cur = it & 1;
    const ushort_t* kbuf = &Kt[cur][0];
    const ushort_t* vbuf = &Vt[cur][0];

    // ---- S^T[k][q]: A = K-frag (row k=lc, c=hd), B = Q^T-frag ----
    f32x16 s0, s1;
#pragma unroll
    for (int i = 0; i < 16; ++i) { s0[i] = 0.f; s1[i] = 0.f; }
    __builtin_amdgcn_s_setprio(1);
#pragma unroll
    for (int st = 0; st < 4; ++st) {
      bf16x8 kf0 = *(const bf16x8*)&kbuf[lc * 64 + (((2 * st + hi) ^ (lc & 7)) << 3)];
      s0 = __builtin_amdgcn_mfma_f32_32x32x16_bf16(kf0, qf[st], s0, 0, 0, 0);
    }
#pragma unroll
    for (int st = 0; st < 4; ++st) {
      bf16x8 kf1 = *(const bf16x8*)&kbuf[(32 + lc) * 64 + (((2 * st + hi) ^ (lc & 7)) << 3)];
      s1 = __builtin_amdgcn_mfma_f32_32x32x16_bf16(kf1, qf[st], s1, 0, 0, 0);
    }
    __builtin_amdgcn_s_setprio(0);

    // ---- causal mask: only the diagonal tile crosses ----
    if (kt * 64 + 63 > q32) {
      const int q = q32 + lc;
#pragma unroll
      for (int r = 0; r < 16; ++r) {
        int cr = (r & 3) + 8 * (r >> 2) + 4 * hi;
        if (kt * 64 + cr > q)      s0[r] = -3.0e38f;
        if (kt * 64 + 32 + cr > q) s1[r] = -3.0e38f;
      }
    }

    // ---- tile max (in-lane tree + cross-half) ----
    float tm[8];
#pragma unroll
    for (int i = 0; i < 8; ++i) tm[i] = fmaxf(fmaxf(s0[i], s0[i + 8]), fmaxf(s1[i], s1[i + 8]));
#pragma unroll
    for (int i = 0; i < 4; ++i) tm[i] = fmaxf(tm[i], tm[i + 4]);
    float tmax = fmaxf(fmaxf(tm[0], tm[1]), fmaxf(tm[2], tm[3]));
    tmax = fmaxf(tmax, __shfl_xor(tmax, 32));

    // ---- T13 defer-max rescale (log2 domain, THR=11; rare with mrun=0) ----
    if (!__all(tmax <= mrun + 11.0f)) {
      float mnew = fmaxf(mrun, tmax);
      float sc = fast_exp2(mrun - mnew);
      lrun *= sc; mrun = mnew;
#pragma unroll
      for (int r = 0; r < 16; ++r) {
        int cr = (r & 3) + 8 * (r >> 2) + 4 * hi;
        float scr = __shfl(sc, cr);
        o0[r] *= scr; o1[r] *= scr;
      }
    }

    // ---- P = exp2(S - m), partial row-sums (deferred cross-half) ----
#pragma unroll
    for (int r = 0; r < 16; ++r) s0[r] = fast_exp2(s0[r] - mrun);
#pragma unroll
    for (int r = 0; r < 16; ++r) s1[r] = fast_exp2(s1[r] - mrun);
    {
      float u0 = 0.f, u1 = 0.f, u2 = 0.f, u3 = 0.f;
#pragma unroll
      for (int i = 0; i < 4; ++i) {
        u0 += s0[i];     u1 += s0[i + 4];  u2 += s0[i + 8];  u3 += s0[i + 12];
        u0 += s1[i];     u1 += s1[i + 4];  u2 += s1[i + 8];  u3 += s1[i + 12];
      }
      lrun += (u0 + u1) + (u2 + u3);
    }

    // ---- pack P to bf16 pairs; permlane32_swap redistributes to A-frags ----
    unsigned wv[16];
#pragma unroll
    for (int i = 0; i < 8; ++i) {
      asm("v_cvt_pk_bf16_f32 %0, %1, %2" : "=v"(wv[i])     : "v"(s0[2 * i]), "v"(s0[2 * i + 1]));
      asm("v_cvt_pk_bf16_f32 %0, %1, %2" : "=v"(wv[8 + i]) : "v"(s1[2 * i]), "v"(s1[2 * i + 1]));
    }
    bf16x8 pf[4];
#pragma unroll
    for (int g4 = 0; g4 < 4; ++g4) {
      unsigned a0 = wv[4 * g4], a1 = wv[4 * g4 + 1];
      unsigned a2 = wv[4 * g4 + 2], a3 = wv[4 * g4 + 3];
      asm("v_permlane32_swap_b32 %0, %1" : "+v"(a0), "+v"(a2));
      asm("v_permlane32_swap_b32 %0, %1" : "+v"(a1), "+v"(a3));
      uint4v fw; fw[0] = a0; fw[1] = a1; fw[2] = a2; fw[3] = a3;
      pf[g4] = __builtin_bit_cast(bf16x8, fw);
    }

    // ---- O += P V (V from [d][k] granule-swizzled LDS, b128 reads) ----
    __builtin_amdgcn_s_setprio(1);
#pragma unroll
    for (int km = 0; km < 4; ++km) {
      int gsl = ((2 * km + hi) ^ (lc & 7)) << 3;
      bf16x8 vb0 = *(const bf16x8*)&vbuf[lc * 64 + gsl];
      bf16x8 vb1 = *(const bf16x8*)&vbuf[(32 + lc) * 64 + gsl];
      o0 = __builtin_amdgcn_mfma_f32_32x32x16_bf16(pf[km], vb0, o0, 0, 0, 0);
      o1 = __builtin_amdgcn_mfma_f32_32x32x16_bf16(pf[km], vb1, o1, 0, 0, 0);
    }
    __builtin_amdgcn_s_setprio(0);

    // ---- stage next tile (other buffer), issue tile after next ----
    if (it + 1 < total) stage_write((it + 1) & 1);
    if (it + 2 < total) {
      int itn = it + 2;
      stage_issue((itn < nktA) ? itn : itn - nktA);
    }
    __syncthreads();
  }

  epilogue();
}

extern "C" void kernel_launch(void* const* d_in, const int* in_sizes, int n_in,
                              void* d_out, int out_size, void* d_ws, size_t ws_size,
                              hipStream_t stream) {
  const float* x     = (const float*)d_in[0];
  const float* Wqkv  = (const float*)d_in[1];
  const float* Wproj = (const float*)d_in[2];
  float* out = (float*)d_out;
  ushort_t* ws = (ushort_t*)d_ws;

  ushort_t* Xb  = ws;
  ushort_t* WqT = Xb  + (size_t)MROWS * D_DIM;        // 8192*1024
  ushort_t* WpT = WqT + (size_t)3 * D_DIM * D_DIM;    // 3072*1024
  ushort_t* Qb  = WpT + (size_t)D_DIM * D_DIM;        // 1024*1024
  ushort_t* Kb  = Qb + PERQKV;
  ushort_t* Vb  = Kb + PERQKV;
  ushort_t* Yb  = Vb + PERQKV;

  k_cvt_x<<<(MROWS * D_DIM / 4) / 256, 256, 0, stream>>>(x, Xb);
  k_transpose<<<dim3(3 * D_DIM / 32, D_DIM / 32), 256, 0, stream>>>(Wqkv, WqT, D_DIM, 3 * D_DIM);
  k_transpose<<<dim3(D_DIM / 32, D_DIM / 32), 256, 0, stream>>>(Wproj, WpT, D_DIM, D_DIM);
  k_gemm<3 * D_DIM, D_DIM, 0><<<dim3(3 * D_DIM / 128, MROWS / 128), 256, 0, stream>>>(Xb, WqT, Qb, nullptr);
  k_attn<<<1024, 128, 0, stream>>>(Qb, Kb, Vb, Yb);
  k_gemm<D_DIM, D_DIM, 1><<<dim3(D_DIM / 128, MROWS / 128), 256, 0, stream>>>(Yb, WpT, nullptr, out);
}